// Round 12
// baseline (71.821 us; speedup 1.0000x reference)
//
#include <hip/hip_runtime.h>
#include <math.h>

#define BB 256
#define LL 8
#define DD 200
#define NN 100000
#define BN 32                        // concepts per tile (100000 % 32 == 0)
#define NTILE (NN / BN)              // 3125 tiles = sim grid
#define NGRAN 28                     // 16B bf16 granules per row (K padded to 224)
#define NCAND 6

typedef __attribute__((ext_vector_type(8))) __bf16 bf16x8;
typedef __attribute__((ext_vector_type(16))) float f32x16;

// fp32 -> bf16 round-to-nearest-even
__device__ __forceinline__ unsigned f2bf(float x) {
  unsigned u = __float_as_uint(x);
  u = (u + 0x7fffu + ((u >> 16) & 1u)) >> 16;
  return u;
}
__device__ __forceinline__ unsigned pk(float a, float b) {
  return f2bf(a) | (f2bf(b) << 16);
}
// numpy argmax semantics: larger wins; exact tie -> smaller index
__device__ __forceinline__ bool better(float a, int ia, float b, int ib) {
  return (a > b) || (a == b && ia < ib);
}
__device__ __forceinline__ float dot4(float4 f) {
  return f.x * f.x + f.y * f.y + f.z * f.z + f.w * f.w;
}

// ------------- Kernel 1: mention rep (fp32 + bf16 granule-major) -------------
// abfT layout: uint4 unit index g*256 + m
__global__ __launch_bounds__(256) void prep_kernel(
    const int* __restrict__ ids, const float* __restrict__ we,
    float* __restrict__ repf, unsigned short* __restrict__ abf,
    float* __restrict__ mnorm) {
  int m = blockIdx.x, d = threadIdx.x;
  __shared__ float red[4];
  float r = 0.f;
  if (d < DD) {
    int base = m * LL;
#pragma unroll
    for (int l2 = 0; l2 < LL; ++l2) r += we[(size_t)ids[base + l2] * DD + d];
    r *= 0.125f;
    repf[m * DD + d] = r;
  }
  if (d < NGRAN * 8) {
    int g = d >> 3, wo = d & 7;
    abf[(g * 256 + m) * 8 + wo] = (unsigned short)f2bf(d < DD ? r : 0.f);
  }
  float sq = (d < DD) ? r * r : 0.f;
#pragma unroll
  for (int off = 32; off; off >>= 1) sq += __shfl_down(sq, off);
  if ((threadIdx.x & 63) == 0) red[threadIdx.x >> 6] = sq;
  __syncthreads();
  if (threadIdx.x == 0) mnorm[m] = sqrtf(red[0] + red[1] + red[2] + red[3]);
}

// ------------- Kernel 2: one tile per block (no serial chain) ----------------
// R11 lesson: the grid-stride ring exposed ~6 serial rounds of load latency +
// BW convoy per block. One independent tile per block lets the HW dispatcher
// pipeline memory across retiring/launching blocks continuously.
// Plain __launch_bounds__(512): R3/R11-proven regime where areg stays
// resident (VGPR~96-112); (512,4) builds collapsed to 64 VGPR (R8-R10).
__global__ __launch_bounds__(512) void sim_kernel(
    const float* __restrict__ dict, const uint4* __restrict__ abfT,
    float4* __restrict__ partial) {
  __shared__ uint4 Bs[NGRAN * BN];     // 14 KB, single buffer
  int tid = threadIdx.x;
  int w = tid >> 6, l = tid & 63;
  int ln = l & 31, kh = l >> 5;
  int m = w * 32 + ln;
  int tile = blockIdx.x;

  // staging role: 32 rows x 16 parts
  int row = tid >> 4, part = tid & 15;
  const bool extra = (part < 2);
  int g0i = part >> 1, h = part & 1;

  // ---- issue dict loads (longest latency) ----
  const float* src = dict + (size_t)(tile * BN + row) * DD;
  float4 f0 = *(const float4*)(src + 4 * part);
  float4 f1 = *(const float4*)(src + 64 + 4 * part);
  float4 f2 = *(const float4*)(src + 128 + 4 * part);
  float4 f3 = extra ? *(const float4*)(src + 192 + 4 * part)
                    : make_float4(0.f, 0.f, 0.f, 0.f);

  // ---- mention fragments (L2-resident, independent of dict loads) ----
  uint4 areg[14];
#pragma unroll
  for (int j = 0; j < 14; ++j) areg[j] = abfT[(2 * j + kh) * 256 + m];
#pragma unroll
  for (int j = 0; j < 14; ++j)
    asm volatile("" : "+v"(areg[j].x), "+v"(areg[j].y),
                      "+v"(areg[j].z), "+v"(areg[j].w));

  // zero-pad granules 25..27 (k 200..223)
  if (tid < 96) {
    int g = 25 + tid / 32, r = tid & 31;
    Bs[g * 32 + (r ^ (g & 7))] = make_uint4(0, 0, 0, 0);
  }

  // ---- normalize + convert + stage ----
  {
    float sq = dot4(f0) + dot4(f1) + dot4(f2) + dot4(f3);
    sq += __shfl_xor(sq, 1); sq += __shfl_xor(sq, 2);
    sq += __shfl_xor(sq, 4); sq += __shfl_xor(sq, 8);
    float rs = 1.0f / fmaxf(sqrtf(sq), 1e-8f);
    uint2* B2 = (uint2*)&Bs[0];
    B2[(g0i * 32 + (row ^ (g0i & 7))) * 2 + h] =
        make_uint2(pk(f0.x * rs, f0.y * rs), pk(f0.z * rs, f0.w * rs));
    int ga = 8 + g0i;
    B2[(ga * 32 + (row ^ (ga & 7))) * 2 + h] =
        make_uint2(pk(f1.x * rs, f1.y * rs), pk(f1.z * rs, f1.w * rs));
    int gb = 16 + g0i;
    B2[(gb * 32 + (row ^ (gb & 7))) * 2 + h] =
        make_uint2(pk(f2.x * rs, f2.y * rs), pk(f2.z * rs, f2.w * rs));
    if (extra)
      B2[(24 * 32 + row) * 2 + part] =
          make_uint2(pk(f3.x * rs, f3.y * rs), pk(f3.z * rs, f3.w * rs));
  }
  __syncthreads();

  // ---- 14 MFMA over the tile ----
  f32x16 acc;
#pragma unroll
  for (int i = 0; i < 16; ++i) acc[i] = 0.f;
#pragma unroll
  for (int j = 0; j < 14; ++j) {
    int g = 2 * j + kh;
    bf16x8 a = __builtin_bit_cast(bf16x8, Bs[g * 32 + (ln ^ (g & 7))]);
    acc = __builtin_amdgcn_mfma_f32_32x32x16_bf16(
        a, __builtin_bit_cast(bf16x8, areg[j]), acc, 0, 0, 0);
  }

  // ---- lane-local top-2 (monotone n order -> numpy tie semantics) ----
  float v1 = -INFINITY, v2 = -INFINITY;
  int i1 = 0x7fffffff, i2 = 0x7fffffff;
  int n0 = tile * BN + 4 * kh;
#pragma unroll
  for (int r = 0; r < 16; ++r) {
    int n = n0 + (r & 3) + 8 * (r >> 2);
    float v = acc[r];
    if (v > v1) { v2 = v1; i2 = i1; v1 = v; i1 = n; }
    else if (v > v2) { v2 = v; i2 = n; }
  }
  // merge the two kh halves (same m, disjoint n)
  float w1 = __shfl_xor(v1, 32); int j1 = __shfl_xor(i1, 32);
  float w2 = __shfl_xor(v2, 32); int j2 = __shfl_xor(i2, 32);
  float o1, o2; int oi1, oi2;
  if (better(w1, j1, v1, i1)) {
    bool tt = better(v1, i1, w2, j2);
    o1 = w1; oi1 = j1; o2 = tt ? v1 : w2; oi2 = tt ? i1 : j2;
  } else {
    bool tt = better(w1, j1, v2, i2);
    o1 = v1; oi1 = i1; o2 = tt ? w1 : v2; oi2 = tt ? j1 : i2;
  }
  if (kh == 0)
    partial[(size_t)m * NTILE + tile] =
        make_float4(o1, __int_as_float(oi1), o2, __int_as_float(oi2));
}

// ------------- Kernel 3: top-6 select + exact fp32 rescore -------------------
__global__ __launch_bounds__(256) void final_kernel(
    const float* __restrict__ dict, const float* __restrict__ repf,
    const float* __restrict__ mnorm, const float4* __restrict__ partial,
    float* __restrict__ out) {
  int m = blockIdx.x, tid = threadIdx.x;
  __shared__ float repL[DD];
  __shared__ int seln[NCAND];
  __shared__ float wv[4]; __shared__ int wi[4];
  __shared__ float finv[NCAND]; __shared__ int finn[NCAND];
  if (tid < DD) repL[tid] = repf[m * DD + tid];
  __syncthreads();

  const float4* pm = partial + (size_t)m * NTILE;
  for (int r = 0; r < NCAND; ++r) {
    float bv = -INFINITY; int bi = 0x7fffffff;
#pragma unroll
    for (int e = 0; e < 13; ++e) {           // ceil(3125/256)=13, L2-warm re-read
      int idx = tid + e * 256;
      if (idx < NTILE) {
        float4 E = pm[idx];
        float a1 = E.x; int c1 = __float_as_int(E.y);
        float a2 = E.z; int c2 = __float_as_int(E.w);
        bool ex1 = false, ex2 = false;
        for (int j = 0; j < r; ++j) {
          int s = seln[j];
          ex1 |= (s == c1); ex2 |= (s == c2);
        }
        if (!ex1 && better(a1, c1, bv, bi)) { bv = a1; bi = c1; }
        if (!ex2 && better(a2, c2, bv, bi)) { bv = a2; bi = c2; }
      }
    }
#pragma unroll
    for (int off = 1; off < 64; off <<= 1) {
      float ov = __shfl_xor(bv, off); int oi = __shfl_xor(bi, off);
      if (better(ov, oi, bv, bi)) { bv = ov; bi = oi; }
    }
    if ((tid & 63) == 0) { wv[tid >> 6] = bv; wi[tid >> 6] = bi; }
    __syncthreads();
    if (tid == 0) {
      float Bv = wv[0]; int Bi = wi[0];
#pragma unroll
      for (int q = 1; q < 4; ++q)
        if (better(wv[q], wi[q], Bv, Bi)) { Bv = wv[q]; Bi = wi[q]; }
      seln[r] = Bi;
    }
    __syncthreads();
  }

  // exact fp32 rescore: one 32-lane group per candidate
  int g = tid >> 5, lane = tid & 31;
  int n = (g < NCAND) ? seln[g] : -1;
  float s1 = 0.f, s2 = 0.f;
  if (n >= 0) {
    for (int d = lane; d < DD; d += 32) {
      float b = dict[(size_t)n * DD + d];
      s1 += repL[d] * b; s2 += b * b;
    }
  }
#pragma unroll
  for (int off = 1; off < 32; off <<= 1) {
    s1 += __shfl_xor(s1, off); s2 += __shfl_xor(s2, off);
  }
  if (lane == 0 && g < NCAND) {
    finv[g] = (n >= 0) ? s1 / fmaxf(mnorm[m] * sqrtf(s2), 1e-8f) : -INFINITY;
    finn[g] = n;
  }
  __syncthreads();
  if (tid == 0) {
    float Bv = finv[0]; int Bi = finn[0];
#pragma unroll
    for (int q = 1; q < NCAND; ++q)
      if (better(finv[q], finn[q], Bv, Bi)) { Bv = finv[q]; Bi = finn[q]; }
    out[m] = Bv;
    out[BB + m] = (float)Bi;  // indices as f32 (flat f32 readback)
  }
}

extern "C" void kernel_launch(void* const* d_in, const int* in_sizes, int n_in,
                              void* d_out, int out_size, void* d_ws, size_t ws_size,
                              hipStream_t stream) {
  const int* ids = (const int*)d_in[0];
  const float* we = (const float*)d_in[1];
  const float* dict = (const float*)d_in[2];
  float* out = (float*)d_out;

  char* ws = (char*)d_ws;
  unsigned short* abf = (unsigned short*)ws;              // 28*256*16 = 114,688
  float* repf  = (float*)(ws + 114688);                   // 204,800
  float* mnorm = (float*)(ws + 319488);                   // 1,024
  float4* partial = (float4*)(ws + 320512);               // 256*3125*16 = 12,800,000

  prep_kernel<<<BB, 256, 0, stream>>>(ids, we, repf, abf, mnorm);
  sim_kernel<<<NTILE, 512, 0, stream>>>(dict, (const uint4*)abf, partial);
  final_kernel<<<BB, 256, 0, stream>>>(dict, repf, mnorm, partial, out);
}

// Round 13
// 56.542 us; speedup vs baseline: 1.2702x; 1.2702x over previous
//
#include <hip/hip_runtime.h>
#include <math.h>

#define BB 256
#define LL 8
#define DD 200
#define NN 100000
#define BN 32                        // concepts per tile (100000 % 32 == 0)
#define NTILE (NN / BN)              // 3125
#define NGRAN 28                     // 16B bf16 granules per row (K padded to 224)
#define RAWU 1600                    // 16B units per raw fp32 tile (32*200*4/16)
#define GRID_SIM 512
#define NCAND 6

typedef __attribute__((ext_vector_type(8))) __bf16 bf16x8;
typedef __attribute__((ext_vector_type(16))) float f32x16;

// fp32 -> bf16 round-to-nearest-even
__device__ __forceinline__ unsigned f2bf(float x) {
  unsigned u = __float_as_uint(x);
  u = (u + 0x7fffu + ((u >> 16) & 1u)) >> 16;
  return u;
}
__device__ __forceinline__ unsigned pk(float a, float b) {
  return f2bf(a) | (f2bf(b) << 16);
}
// numpy argmax semantics: larger wins; exact tie -> smaller index
__device__ __forceinline__ bool better(float a, int ia, float b, int ib) {
  return (a > b) || (a == b && ia < ib);
}
__device__ __forceinline__ float dot4(float4 f) {
  return f.x * f.x + f.y * f.y + f.z * f.z + f.w * f.w;
}
// async global->LDS, 16B per lane, dest = wave-uniform base + lane*16
__device__ __forceinline__ void glds16(const void* g, void* l) {
  __builtin_amdgcn_global_load_lds(
      (const __attribute__((address_space(1))) unsigned int*)g,
      (__attribute__((address_space(3))) unsigned int*)l, 16, 0, 0);
}

// ------------- Kernel 1: mention rep (fp32 + bf16 granule-major) -------------
__global__ __launch_bounds__(256) void prep_kernel(
    const int* __restrict__ ids, const float* __restrict__ we,
    float* __restrict__ repf, unsigned short* __restrict__ abf,
    float* __restrict__ mnorm) {
  int m = blockIdx.x, d = threadIdx.x;
  __shared__ float red[4];
  float r = 0.f;
  if (d < DD) {
    int base = m * LL;
#pragma unroll
    for (int l2 = 0; l2 < LL; ++l2) r += we[(size_t)ids[base + l2] * DD + d];
    r *= 0.125f;
    repf[m * DD + d] = r;
  }
  if (d < NGRAN * 8) {
    int g = d >> 3, wo = d & 7;
    abf[(g * 256 + m) * 8 + wo] = (unsigned short)f2bf(d < DD ? r : 0.f);
  }
  float sq = (d < DD) ? r * r : 0.f;
#pragma unroll
  for (int off = 32; off; off >>= 1) sq += __shfl_down(sq, off);
  if ((threadIdx.x & 63) == 0) red[threadIdx.x >> 6] = sq;
  __syncthreads();
  if (threadIdx.x == 0) mnorm[m] = sqrtf(red[0] + red[1] + red[2] + red[3]);
}

// ------------- Kernel 2: glds-staged fused convert+MFMA sims -----------------
// Ring over tiles t ≡ blockIdx (mod 512). Staging = global_load_lds of the
// RAW fp32 tile (contiguous 25.6KB, zero VALU, zero staging regs); convert
// (norm + fp32->bf16) runs LDS->LDS off the global critical path. Waves wait
// only at vmcnt(0) = the pure BW floor. areg held by an IN-LOOP "+v" pin:
// loop-carried asm dependence the allocator cannot satisfy via re-load
// (R9/R12: prologue pins were ignored, VGPR collapsed to 48-64).
__global__ __launch_bounds__(512) void sim_kernel(
    const float* __restrict__ dict, const uint4* __restrict__ abfT,
    float4* __restrict__ partial) {
  __shared__ uint4 Raw[2][RAWU];       // 2 x 25.6 KB raw fp32 ring
  __shared__ uint4 Bsb[NGRAN * BN];    // 14 KB bf16 (normalized), single

  int tid = threadIdx.x;
  int w = tid >> 6, l = tid & 63;
  int ln = l & 31, kh = l >> 5;
  int m = w * 32 + ln;

  // mention fragments (L2-resident load, once)
  uint4 areg[14];
#pragma unroll
  for (int j = 0; j < 14; ++j) areg[j] = abfT[(2 * j + kh) * 256 + m];

  // zero-pad bf granules 25..27 (k 200..223), written once
  if (tid < 96) {
    int g = 25 + tid / 32, r = tid & 31;
    Bsb[g * 32 + (r ^ (g & 7))] = make_uint4(0, 0, 0, 0);
  }

  // convert-phase role: 16 threads per row
  int row = tid >> 4, p = tid & 15;
  const bool two = (p < 9);            // p handles granules {p, 16+p(<25)}

  float v1 = -INFINITY, v2 = -INFINITY;
  int i1 = 0x7fffffff, i2 = 0x7fffffff;

  int t0 = blockIdx.x;
  // ---- prologue: glds tile t0 -> Raw[0] ----
  {
    const char* src = (const char*)dict + (size_t)t0 * 25600;
#pragma unroll
    for (int i = 0; i < 3; ++i) {
      int u0 = i * 512 + w * 64;
      glds16(src + (u0 + l) * 16, (char*)&Raw[0][0] + u0 * 16);
    }
    if (w == 0) glds16(src + (1536 + l) * 16, (char*)&Raw[0][0] + 1536 * 16);
  }
  asm volatile("s_waitcnt vmcnt(0)" ::: "memory");
  __builtin_amdgcn_sched_barrier(0);
  __syncthreads();

  int cur = 0;
  for (int t = t0; t < NTILE; t += GRID_SIM) {
    bool hn = (t + GRID_SIM) < NTILE;
    if (hn) {  // issue next tile's glds into the other raw buffer
      const char* src = (const char*)dict + (size_t)(t + GRID_SIM) * 25600;
      char* dst = (char*)&Raw[cur ^ 1][0];
#pragma unroll
      for (int i = 0; i < 3; ++i) {
        int u0 = i * 512 + w * 64;
        glds16(src + (u0 + l) * 16, dst + u0 * 16);
      }
      if (w == 0) glds16(src + (1536 + l) * 16, dst + 1536 * 16);
    }

    // ---- convert Raw[cur] -> Bsb: row norm + fp32->bf16, all in LDS ----
    {
      const float* rrow = (const float*)&Raw[cur][0] + row * 200;
      float4 a0 = *(const float4*)(rrow + p * 8);
      float4 a1 = *(const float4*)(rrow + p * 8 + 4);
      float4 b0 = make_float4(0.f, 0.f, 0.f, 0.f), b1 = b0;
      if (two) {
        b0 = *(const float4*)(rrow + 128 + p * 8);
        b1 = *(const float4*)(rrow + 128 + p * 8 + 4);
      }
      float sq = dot4(a0) + dot4(a1) + dot4(b0) + dot4(b1);
      sq += __shfl_xor(sq, 1); sq += __shfl_xor(sq, 2);
      sq += __shfl_xor(sq, 4); sq += __shfl_xor(sq, 8);
      float rs = 1.0f / fmaxf(sqrtf(sq), 1e-8f);
      Bsb[p * 32 + (row ^ (p & 7))] =
          make_uint4(pk(a0.x * rs, a0.y * rs), pk(a0.z * rs, a0.w * rs),
                     pk(a1.x * rs, a1.y * rs), pk(a1.z * rs, a1.w * rs));
      if (two) {
        int g = 16 + p;
        Bsb[g * 32 + (row ^ (g & 7))] =
            make_uint4(pk(b0.x * rs, b0.y * rs), pk(b0.z * rs, b0.w * rs),
                       pk(b1.x * rs, b1.y * rs), pk(b1.z * rs, b1.w * rs));
      }
    }
    __syncthreads();   // Bsb ready

    // in-loop pin: loop-carried register dependence -> areg stays resident
#pragma unroll
    for (int j = 0; j < 14; ++j)
      asm volatile("" : "+v"(areg[j].x), "+v"(areg[j].y),
                        "+v"(areg[j].z), "+v"(areg[j].w));

    f32x16 acc;
#pragma unroll
    for (int i = 0; i < 16; ++i) acc[i] = 0.f;
#pragma unroll
    for (int j = 0; j < 14; ++j) {
      int g = 2 * j + kh;
      bf16x8 a = __builtin_bit_cast(bf16x8, Bsb[g * 32 + (ln ^ (g & 7))]);
      acc = __builtin_amdgcn_mfma_f32_32x32x16_bf16(
          a, __builtin_bit_cast(bf16x8, areg[j]), acc, 0, 0, 0);
    }

    // lane-local running top-2 (n monotone -> numpy tie semantics)
    int n0 = t * BN + 4 * kh;
#pragma unroll
    for (int r = 0; r < 16; ++r) {
      int n = n0 + (r & 3) + 8 * (r >> 2);
      float v = acc[r];
      if (v > v1) { v2 = v1; i2 = i1; v1 = v; i1 = n; }
      else if (v > v2) { v2 = v; i2 = n; }
    }

    if (hn) {
      asm volatile("s_waitcnt vmcnt(0)" ::: "memory");  // t+1 glds landed
      __builtin_amdgcn_sched_barrier(0);
      __syncthreads();   // Bsb consumed + Raw[cur^1] published
    }
    cur ^= 1;
  }

  // merge the two kh halves (same m, disjoint n)
  float w1 = __shfl_xor(v1, 32); int j1 = __shfl_xor(i1, 32);
  float w2 = __shfl_xor(v2, 32); int j2 = __shfl_xor(i2, 32);
  float o1, o2; int oi1, oi2;
  if (better(w1, j1, v1, i1)) {
    bool tt = better(v1, i1, w2, j2);
    o1 = w1; oi1 = j1; o2 = tt ? v1 : w2; oi2 = tt ? i1 : j2;
  } else {
    bool tt = better(w1, j1, v2, i2);
    o1 = v1; oi1 = i1; o2 = tt ? w1 : v2; oi2 = tt ? j1 : i2;
  }
  if (kh == 0)
    partial[(size_t)m * GRID_SIM + blockIdx.x] =
        make_float4(o1, __int_as_float(oi1), o2, __int_as_float(oi2));
}

// ------------- Kernel 3: top-6 select + exact fp32 rescore -------------------
__global__ __launch_bounds__(256) void final_kernel(
    const float* __restrict__ dict, const float* __restrict__ repf,
    const float* __restrict__ mnorm, const float4* __restrict__ partial,
    float* __restrict__ out) {
  int m = blockIdx.x, tid = threadIdx.x;
  __shared__ float repL[DD];
  __shared__ int seln[NCAND];
  __shared__ float wv[4]; __shared__ int wi[4];
  __shared__ float finv[NCAND]; __shared__ int finn[NCAND];
  if (tid < DD) repL[tid] = repf[m * DD + tid];
  __syncthreads();

  const float4* pm = partial + (size_t)m * GRID_SIM;
  float cv1[2], cv2[2]; int ci1[2], ci2[2];
#pragma unroll
  for (int e = 0; e < 2; ++e) {
    float4 E = pm[tid + e * 256];
    cv1[e] = E.x; ci1[e] = __float_as_int(E.y);
    cv2[e] = E.z; ci2[e] = __float_as_int(E.w);
  }

  for (int r = 0; r < NCAND; ++r) {
    float bv = -INFINITY; int bi = 0x7fffffff;
#pragma unroll
    for (int e = 0; e < 2; ++e) {
      bool ex1 = false, ex2 = false;
      for (int j = 0; j < r; ++j) {
        int s = seln[j];
        ex1 |= (s == ci1[e]); ex2 |= (s == ci2[e]);
      }
      if (!ex1 && better(cv1[e], ci1[e], bv, bi)) { bv = cv1[e]; bi = ci1[e]; }
      if (!ex2 && better(cv2[e], ci2[e], bv, bi)) { bv = cv2[e]; bi = ci2[e]; }
    }
#pragma unroll
    for (int off = 1; off < 64; off <<= 1) {
      float ov = __shfl_xor(bv, off); int oi = __shfl_xor(bi, off);
      if (better(ov, oi, bv, bi)) { bv = ov; bi = oi; }
    }
    if ((tid & 63) == 0) { wv[tid >> 6] = bv; wi[tid >> 6] = bi; }
    __syncthreads();
    if (tid == 0) {
      float Bv = wv[0]; int Bi = wi[0];
#pragma unroll
      for (int q = 1; q < 4; ++q)
        if (better(wv[q], wi[q], Bv, Bi)) { Bv = wv[q]; Bi = wi[q]; }
      seln[r] = Bi;
    }
    __syncthreads();
  }

  // exact fp32 rescore: one 32-lane group per candidate
  int g = tid >> 5, lane = tid & 31;
  int n = (g < NCAND) ? seln[g] : -1;
  float s1 = 0.f, s2 = 0.f;
  if (n >= 0) {
    for (int d = lane; d < DD; d += 32) {
      float b = dict[(size_t)n * DD + d];
      s1 += repL[d] * b; s2 += b * b;
    }
  }
#pragma unroll
  for (int off = 1; off < 32; off <<= 1) {
    s1 += __shfl_xor(s1, off); s2 += __shfl_xor(s2, off);
  }
  if (lane == 0 && g < NCAND) {
    finv[g] = (n >= 0) ? s1 / fmaxf(mnorm[m] * sqrtf(s2), 1e-8f) : -INFINITY;
    finn[g] = n;
  }
  __syncthreads();
  if (tid == 0) {
    float Bv = finv[0]; int Bi = finn[0];
#pragma unroll
    for (int q = 1; q < NCAND; ++q)
      if (better(finv[q], finn[q], Bv, Bi)) { Bv = finv[q]; Bi = finn[q]; }
    out[m] = Bv;
    out[BB + m] = (float)Bi;  // indices as f32 (flat f32 readback)
  }
}

extern "C" void kernel_launch(void* const* d_in, const int* in_sizes, int n_in,
                              void* d_out, int out_size, void* d_ws, size_t ws_size,
                              hipStream_t stream) {
  const int* ids = (const int*)d_in[0];
  const float* we = (const float*)d_in[1];
  const float* dict = (const float*)d_in[2];
  float* out = (float*)d_out;

  char* ws = (char*)d_ws;
  unsigned short* abf = (unsigned short*)ws;              // 28*256*16 = 114,688
  float* repf  = (float*)(ws + 114688);                   // 204,800
  float* mnorm = (float*)(ws + 319488);                   // 1,024
  float4* partial = (float4*)(ws + 320512);               // 256*512*16 = 2,097,152

  prep_kernel<<<BB, 256, 0, stream>>>(ids, we, repf, abf, mnorm);
  sim_kernel<<<GRID_SIM, 512, 0, stream>>>(dict, (const uint4*)abf, partial);
  final_kernel<<<BB, 256, 0, stream>>>(dict, repf, mnorm, partial, out);
}

// Round 14
// 53.040 us; speedup vs baseline: 1.3541x; 1.0660x over previous
//
#include <hip/hip_runtime.h>
#include <math.h>

#define BB 256
#define LL 8
#define DD 200
#define NN 100000
#define BN 32                        // concepts per tile (100000 % 32 == 0)
#define NTILE (NN / BN)              // 3125
#define NGRAN 26                     // granules (16B bf16); 25 = zero pad (K=208)
#define KSTEPS 13                    // MFMA K-steps (2 granules each via kh)
#define GRID_SIM 512
#define NCAND 6

typedef __attribute__((ext_vector_type(8))) __bf16 bf16x8;
typedef __attribute__((ext_vector_type(16))) float f32x16;

__device__ __forceinline__ unsigned f2bf(float x) {
  unsigned u = __float_as_uint(x);
  u = (u + 0x7fffu + ((u >> 16) & 1u)) >> 16;
  return u;
}
__device__ __forceinline__ unsigned pk(float a, float b) {
  return f2bf(a) | (f2bf(b) << 16);
}
__device__ __forceinline__ bool better(float a, int ia, float b, int ib) {
  return (a > b) || (a == b && ia < ib);
}
__device__ __forceinline__ float dot4(float4 f) {
  return f.x * f.x + f.y * f.y + f.z * f.z + f.w * f.w;
}

// ------------- Kernel 1: mention rep (fp32 + bf16 granule-major) -------------
__global__ __launch_bounds__(256) void prep_kernel(
    const int* __restrict__ ids, const float* __restrict__ we,
    float* __restrict__ repf, unsigned short* __restrict__ abf,
    float* __restrict__ mnorm) {
  int m = blockIdx.x, d = threadIdx.x;
  __shared__ float red[4];
  float r = 0.f;
  if (d < DD) {
    int base = m * LL;
#pragma unroll
    for (int l2 = 0; l2 < LL; ++l2) r += we[(size_t)ids[base + l2] * DD + d];
    r *= 0.125f;
    repf[m * DD + d] = r;
  }
  if (d < NGRAN * 8) {
    int g = d >> 3, wo = d & 7;
    abf[(g * 256 + m) * 8 + wo] = (unsigned short)f2bf(d < DD ? r : 0.f);
  }
  float sq = (d < DD) ? r * r : 0.f;
#pragma unroll
  for (int off = 32; off; off >>= 1) sq += __shfl_down(sq, off);
  if ((threadIdx.x & 63) == 0) red[threadIdx.x >> 6] = sq;
  __syncthreads();
  if (threadIdx.x == 0) mnorm[m] = sqrtf(red[0] + red[1] + red[2] + red[3]);
}

// ------------- Kernel 2: 2-deep software-pipelined MFMA sims -----------------
// R13 post-mortem: every vmcnt(0)-per-iteration structure runs at ~7.7us per
// 25.6KB tile (4x BW-share) -- stop-and-go delivery. Here loads for tile i+2
// are issued at body i and consumed (convert) at body i+1: register-dependency
// vmcnt waits give counted-vmcnt semantics, loads stay in flight across the
// barrier, delivery is continuous. One barrier per body.
__device__ __forceinline__ void issue_tile(const float* __restrict__ dict,
                                           int tile, int row, int p, bool extra,
                                           float4& f0, float4& f1, float4& f2,
                                           float4& f3) {
  const float* src = dict + (size_t)(tile * BN + row) * DD;
  f0 = *(const float4*)(src + 4 * p);
  f1 = *(const float4*)(src + 64 + 4 * p);
  f2 = *(const float4*)(src + 128 + 4 * p);
  f3 = extra ? *(const float4*)(src + 192 + 4 * p)
             : make_float4(0.f, 0.f, 0.f, 0.f);
}

__device__ __forceinline__ void convert_tile(float4 f0, float4 f1, float4 f2,
                                             float4 f3, uint4* __restrict__ B,
                                             int row, int p, bool extra,
                                             int g0i, int h) {
  float sq = dot4(f0) + dot4(f1) + dot4(f2) + dot4(f3);
  sq += __shfl_xor(sq, 1); sq += __shfl_xor(sq, 2);
  sq += __shfl_xor(sq, 4); sq += __shfl_xor(sq, 8);
  float rs = 1.0f / fmaxf(sqrtf(sq), 1e-8f);
  uint2* B2 = (uint2*)B;
  B2[(g0i * 32 + (row ^ (g0i & 7))) * 2 + h] =
      make_uint2(pk(f0.x * rs, f0.y * rs), pk(f0.z * rs, f0.w * rs));
  int ga = 8 + g0i;
  B2[(ga * 32 + (row ^ (ga & 7))) * 2 + h] =
      make_uint2(pk(f1.x * rs, f1.y * rs), pk(f1.z * rs, f1.w * rs));
  int gb = 16 + g0i;
  B2[(gb * 32 + (row ^ (gb & 7))) * 2 + h] =
      make_uint2(pk(f2.x * rs, f2.y * rs), pk(f2.z * rs, f2.w * rs));
  if (extra)
    B2[(24 * 32 + row) * 2 + p] =
        make_uint2(pk(f3.x * rs, f3.y * rs), pk(f3.z * rs, f3.w * rs));
}

__global__ __launch_bounds__(512) void sim_kernel(
    const float* __restrict__ dict, const uint4* __restrict__ abfT,
    float4* __restrict__ partial) {
  __shared__ uint4 Bsb[2][NGRAN * BN];   // 2 x 13 KB bf16 tiles

  int tid = threadIdx.x;
  int w = tid >> 6, l = tid & 63;
  int ln = l & 31, kh = l >> 5;
  int m = w * 32 + ln;
  int row = tid >> 4, p = tid & 15;
  const bool extra = (p < 2);
  int g0i = p >> 1, h = p & 1;

  // mention fragments (resident; in-loop pin enforces -- R13-proven)
  uint4 areg[KSTEPS];
#pragma unroll
  for (int j = 0; j < KSTEPS; ++j) areg[j] = abfT[(2 * j + kh) * 256 + m];

  // zero-pad granule 25 (k 200..207), both buffers, written once
  if (tid < 64) {
    int buf = tid >> 5, r = tid & 31;
    Bsb[buf][25 * 32 + (r ^ 1)] = make_uint4(0, 0, 0, 0);
  }

  float v1 = -INFINITY, v2 = -INFINITY;
  int i1 = 0x7fffffff, i2 = 0x7fffffff;

  int t0 = blockIdx.x;
  int niter = (NTILE - 1 - t0) / GRID_SIM + 1;   // 6 or 7

  float4 A0, A1, A2, A3, B0, B1, B2_, B3;

  // ---- prologue: tiles t0 (set A) and t0+G (set B) in flight ----
  issue_tile(dict, t0, row, p, extra, A0, A1, A2, A3);
  if (niter > 1)
    issue_tile(dict, t0 + GRID_SIM, row, p, extra, B0, B1, B2_, B3);
  convert_tile(A0, A1, A2, A3, Bsb[0], row, p, extra, g0i, h);
  __syncthreads();

#define SIM_BODY(I, FS0, FS1, FS2, FS3, CUR)                                   \
  {                                                                            \
    int t = t0 + (I)*GRID_SIM;                                                 \
    if ((I) + 2 < niter)                                                       \
      issue_tile(dict, t + 2 * GRID_SIM, row, p, extra, FS0, FS1, FS2, FS3);   \
    __builtin_amdgcn_sched_barrier(0);                                         \
    _Pragma("unroll")                                                          \
    for (int j = 0; j < KSTEPS; ++j)                                           \
      asm volatile("" : "+v"(areg[j].x), "+v"(areg[j].y), "+v"(areg[j].z),     \
                        "+v"(areg[j].w));                                      \
    f32x16 acc;                                                                \
    _Pragma("unroll")                                                          \
    for (int q = 0; q < 16; ++q) acc[q] = 0.f;                                 \
    _Pragma("unroll")                                                          \
    for (int j = 0; j < KSTEPS; ++j) {                                         \
      int g = 2 * j + kh;                                                      \
      bf16x8 a =                                                               \
          __builtin_bit_cast(bf16x8, Bsb[CUR][g * 32 + (ln ^ (g & 7))]);       \
      acc = __builtin_amdgcn_mfma_f32_32x32x16_bf16(                           \
          a, __builtin_bit_cast(bf16x8, areg[j]), acc, 0, 0, 0);               \
    }                                                                          \
    int n0 = t * BN + 4 * kh;                                                  \
    _Pragma("unroll")                                                          \
    for (int r = 0; r < 16; ++r) {                                             \
      int n = n0 + (r & 3) + 8 * (r >> 2);                                     \
      float v = acc[r];                                                        \
      if (v > v1) { v2 = v1; i2 = i1; v1 = v; i1 = n; }                        \
      else if (v > v2) { v2 = v; i2 = n; }                                     \
    }                                                                          \
  }

  for (int i = 0; i < niter; i += 2) {
    // even body: compute Bsb[0] (tile i); convert set B (tile i+1) -> Bsb[1]
    SIM_BODY(i, A0, A1, A2, A3, 0)
    if (i + 1 < niter)
      convert_tile(B0, B1, B2_, B3, Bsb[1], row, p, extra, g0i, h);
    __syncthreads();
    if (i + 1 < niter) {
      // odd body: compute Bsb[1] (tile i+1); convert set A (tile i+2) -> Bsb[0]
      SIM_BODY(i + 1, B0, B1, B2_, B3, 1)
      if (i + 2 < niter)
        convert_tile(A0, A1, A2, A3, Bsb[0], row, p, extra, g0i, h);
      __syncthreads();
    }
  }
#undef SIM_BODY

  // merge the two kh halves (same m, disjoint n)
  float w1 = __shfl_xor(v1, 32); int j1 = __shfl_xor(i1, 32);
  float w2 = __shfl_xor(v2, 32); int j2 = __shfl_xor(i2, 32);
  float o1, o2; int oi1, oi2;
  if (better(w1, j1, v1, i1)) {
    bool tt = better(v1, i1, w2, j2);
    o1 = w1; oi1 = j1; o2 = tt ? v1 : w2; oi2 = tt ? i1 : j2;
  } else {
    bool tt = better(w1, j1, v2, i2);
    o1 = v1; oi1 = i1; o2 = tt ? w1 : v2; oi2 = tt ? j1 : i2;
  }
  if (kh == 0)
    partial[(size_t)m * GRID_SIM + blockIdx.x] =
        make_float4(o1, __int_as_float(oi1), o2, __int_as_float(oi2));
}

// ------------- Kernel 3: top-6 select + exact fp32 rescore -------------------
__global__ __launch_bounds__(256) void final_kernel(
    const float* __restrict__ dict, const float* __restrict__ repf,
    const float* __restrict__ mnorm, const float4* __restrict__ partial,
    float* __restrict__ out) {
  int m = blockIdx.x, tid = threadIdx.x;
  __shared__ float repL[DD];
  __shared__ int seln[NCAND];
  __shared__ float wv[4]; __shared__ int wi[4];
  __shared__ float finv[NCAND]; __shared__ int finn[NCAND];
  if (tid < DD) repL[tid] = repf[m * DD + tid];
  __syncthreads();

  const float4* pm = partial + (size_t)m * GRID_SIM;
  float cv1[2], cv2[2]; int ci1[2], ci2[2];
#pragma unroll
  for (int e = 0; e < 2; ++e) {
    float4 E = pm[tid + e * 256];
    cv1[e] = E.x; ci1[e] = __float_as_int(E.y);
    cv2[e] = E.z; ci2[e] = __float_as_int(E.w);
  }

  for (int r = 0; r < NCAND; ++r) {
    float bv = -INFINITY; int bi = 0x7fffffff;
#pragma unroll
    for (int e = 0; e < 2; ++e) {
      bool ex1 = false, ex2 = false;
      for (int j = 0; j < r; ++j) {
        int s = seln[j];
        ex1 |= (s == ci1[e]); ex2 |= (s == ci2[e]);
      }
      if (!ex1 && better(cv1[e], ci1[e], bv, bi)) { bv = cv1[e]; bi = ci1[e]; }
      if (!ex2 && better(cv2[e], ci2[e], bv, bi)) { bv = cv2[e]; bi = ci2[e]; }
    }
#pragma unroll
    for (int off = 1; off < 64; off <<= 1) {
      float ov = __shfl_xor(bv, off); int oi = __shfl_xor(bi, off);
      if (better(ov, oi, bv, bi)) { bv = ov; bi = oi; }
    }
    if ((tid & 63) == 0) { wv[tid >> 6] = bv; wi[tid >> 6] = bi; }
    __syncthreads();
    if (tid == 0) {
      float Bv = wv[0]; int Bi = wi[0];
#pragma unroll
      for (int q = 1; q < 4; ++q)
        if (better(wv[q], wi[q], Bv, Bi)) { Bv = wv[q]; Bi = wi[q]; }
      seln[r] = Bi;
    }
    __syncthreads();
  }

  // exact fp32 rescore: one 32-lane group per candidate
  int g = tid >> 5, lane = tid & 31;
  int n = (g < NCAND) ? seln[g] : -1;
  float s1 = 0.f, s2 = 0.f;
  if (n >= 0) {
    for (int d = lane; d < DD; d += 32) {
      float b = dict[(size_t)n * DD + d];
      s1 += repL[d] * b; s2 += b * b;
    }
  }
#pragma unroll
  for (int off = 1; off < 32; off <<= 1) {
    s1 += __shfl_xor(s1, off); s2 += __shfl_xor(s2, off);
  }
  if (lane == 0 && g < NCAND) {
    finv[g] = (n >= 0) ? s1 / fmaxf(mnorm[m] * sqrtf(s2), 1e-8f) : -INFINITY;
    finn[g] = n;
  }
  __syncthreads();
  if (tid == 0) {
    float Bv = finv[0]; int Bi = finn[0];
#pragma unroll
    for (int q = 1; q < NCAND; ++q)
      if (better(finv[q], finn[q], Bv, Bi)) { Bv = finv[q]; Bi = finn[q]; }
    out[m] = Bv;
    out[BB + m] = (float)Bi;  // indices as f32 (flat f32 readback)
  }
}

extern "C" void kernel_launch(void* const* d_in, const int* in_sizes, int n_in,
                              void* d_out, int out_size, void* d_ws, size_t ws_size,
                              hipStream_t stream) {
  const int* ids = (const int*)d_in[0];
  const float* we = (const float*)d_in[1];
  const float* dict = (const float*)d_in[2];
  float* out = (float*)d_out;

  char* ws = (char*)d_ws;
  unsigned short* abf = (unsigned short*)ws;              // 26*256*16 = 106,496
  float* repf  = (float*)(ws + 106496);                   // 204,800
  float* mnorm = (float*)(ws + 311296);                   // 1,024
  float4* partial = (float4*)(ws + 312320);               // 256*512*16 = 2,097,152

  prep_kernel<<<BB, 256, 0, stream>>>(ids, we, repf, abf, mnorm);
  sim_kernel<<<GRID_SIM, 512, 0, stream>>>(dict, (const uint4*)abf, partial);
  final_kernel<<<BB, 256, 0, stream>>>(dict, repf, mnorm, partial, out);
}